// Round 11
// baseline (155.110 us; speedup 1.0000x reference)
//
#include <hip/hip_runtime.h>
#include <hip/hip_bf16.h>

#define TEMP_INV 14.285714285714286f  // 1/0.07
#define FSCALE 16.0f                  // fp8 pre-scale per operand
#define T1S (TEMP_INV / 256.0f)       // acc = 256*sim -> (sim-1)/T = acc*T1S - TEMP_INV
#define INV_LN2 1.4426950408889634f
#define LN2F 0.6931471805599453f
#define T1S2 (T1S * INV_LN2)          // log2-domain slope
#define TI2  (TEMP_INV * INV_LN2)     // log2-domain offset
#define NS 8                          // column slices per strip

typedef __attribute__((ext_vector_type(4))) float f32x4;
typedef __attribute__((ext_vector_type(4))) int i32x4;
typedef __attribute__((ext_vector_type(8))) int i32x8;

// ---- fq FRAGMENT-MAJOR layout ----
// 2KB tiles: tile(rg, kb), rg = row/16, kb = kbyte/128. Fragment (lane) =
// lo16B at tile+lane*16, hi16B at tile+1024+lane*16 -> two lane-consecutive
// 1KB global loads per fragment.

// ---- row L2-normalize -> fp8 e4m3 (x16) into fragment-major layout ----
// Also zeroes colS/colP (col-side symmetry accumulators) and gacc/dcnt.
__global__ __launch_bounds__(256) void norm_k(const float* __restrict__ feat,
                                              uchar* __restrict__ fq,
                                              const int* __restrict__ labels,
                                              const int* __restrict__ kptr,
                                              int* __restrict__ glab,
                                              float* __restrict__ colS,
                                              float* __restrict__ colP,
                                              float* __restrict__ gacc,
                                              int* __restrict__ dcnt,
                                              int N, int D) {
  const int row = (blockIdx.x * 256 + threadIdx.x) >> 6;
  const int lane = threadIdx.x & 63;
  const int gtid = blockIdx.x * 256 + threadIdx.x;
  if (gtid < N) { colS[gtid] = 0.f; colP[gtid] = 0.f; }
  if (row < N) {
    const float4* fr = (const float4*)(feat + (size_t)row * D);
    float4 v0 = fr[lane * 2];
    float4 v1 = fr[lane * 2 + 1];
    float ss = v0.x * v0.x + v0.y * v0.y + v0.z * v0.z + v0.w * v0.w +
               v1.x * v1.x + v1.y * v1.y + v1.z * v1.z + v1.w * v1.w;
    #pragma unroll
    for (int off = 32; off; off >>= 1) ss += __shfl_xor(ss, off, 64);
    const float inv = FSCALE / fmaxf(sqrtf(ss), 1e-12f);
    int w0 = 0, w1 = 0;
    w0 = __builtin_amdgcn_cvt_pk_fp8_f32(v0.x * inv, v0.y * inv, w0, false);
    w0 = __builtin_amdgcn_cvt_pk_fp8_f32(v0.z * inv, v0.w * inv, w0, true);
    w1 = __builtin_amdgcn_cvt_pk_fp8_f32(v1.x * inv, v1.y * inv, w1, false);
    w1 = __builtin_amdgcn_cvt_pk_fp8_f32(v1.z * inv, v1.w * inv, w1, true);
    uint2 o; o.x = (uint)w0; o.y = (uint)w1;
    const int tkb  = lane >> 4;
    const int quad = (lane >> 2) & 3;
    const int half = (lane >> 1) & 1;
    const int slot = half * 64 + quad * 16 + (row & 15);
    uchar* dstp = fq + (((size_t)(row >> 4) * (D >> 7) + tkb) << 11) +
                  slot * 16 + (lane & 1) * 8;
    *(uint2*)dstp = o;
    if (lane == 0) {
      const int k = *kptr;
      glab[row] = labels[(size_t)(row / k) * k];
    }
  }
  if (blockIdx.x == 0 && threadIdx.x < 3) {
    if (threadIdx.x < 2) gacc[threadIdx.x] = 0.f;
    else *dcnt = 0;
  }
}

// ---- TRIANGLE-flash fused GEMM + online masked-softmax stats ----
// r24: half the MFMA work of r21 (upper triangle at 32x32 granularity) while
// keeping r21's saturated-overlap structure. Wave = 32-row strip; j-steps
// jb >= strip, 32 cols each, sliced 8 ways (slice s: jb = a+s, a+s+8, ...).
// Strip pairing (wave0 = strip p, wave1 = strip 255-p) balances load.
// Per j-step: 8 B-LOADFs (one cluster) + 16 mfma_scale + online row-side
// S/P + col-side symmetry sums (2 adds/elem, 8 shuffles, 64 atomicAdds into
// colS/colP). Diag j-step (jb==a, slice 0) masks col==row, no col-side.
// A-fragments register-cached once per wave. VGPR ~190, 2 waves/SIMD.
__global__ __launch_bounds__(128) void gemm_k(const uchar* __restrict__ fq,
                                              const int* __restrict__ glab,
                                              float* __restrict__ partS,
                                              float* __restrict__ partP,
                                              float* __restrict__ colS,
                                              float* __restrict__ colP,
                                              int N, int D) {
  const int lane = threadIdx.x & 63;
  const int wid  = threadIdx.x >> 6;
  const int quad = lane >> 4, l15 = lane & 15;
  const int ktiles = D >> 7;              // 4 at D=512
  const int nstrips = N >> 5;             // 256
  const int p = (int)(blockIdx.x / NS);   // strip pair 0..127
  const int s = (int)(blockIdx.x % NS);   // column slice 0..7
  const int a = wid ? (nstrips - 1 - p) : p;
  const int r0 = a << 5;

  int rlab[2][4];
  #pragma unroll
  for (int mi = 0; mi < 2; mi++)
    #pragma unroll
    for (int r = 0; r < 4; r++)
      rlab[mi][r] = glab[r0 + mi * 16 + quad * 4 + r];

  float Srun[2][4] = {{0.f, 0.f, 0.f, 0.f}, {0.f, 0.f, 0.f, 0.f}};
  float Prun[2][4] = {{0.f, 0.f, 0.f, 0.f}, {0.f, 0.f, 0.f, 0.f}};  // log2 units

#define LOADF(dst, grp, kt)                                                   \
  {                                                                           \
    const uchar* p_ = fq + (((size_t)((grp) * ktiles + (kt))) << 11) + lane * 16; \
    i32x4* d_ = (i32x4*)&(dst);                                               \
    d_[0] = *(const i32x4*)p_;                                                \
    d_[1] = *(const i32x4*)(p_ + 1024);                                       \
  }

  // epilogue for off-diagonal j-steps: row-side + col-side (symmetry)
#define EPILOG_FAST(c0)                                                       \
  {                                                                           \
    int clab[2];                                                              \
    clab[0] = glab[(c0) + l15];                                               \
    clab[1] = glab[(c0) + 16 + l15];                                          \
    float colE[2] = {0.f, 0.f}, colQ[2] = {0.f, 0.f};                         \
    _Pragma("unroll")                                                         \
    for (int mi = 0; mi < 2; mi++)                                            \
      _Pragma("unroll")                                                       \
      for (int r = 0; r < 4; r++) {                                           \
        const int rl = rlab[mi][r];                                           \
        _Pragma("unroll")                                                     \
        for (int ni = 0; ni < 2; ni++) {                                      \
          const float lg2 = fmaf(acc[mi][ni][r], T1S2, -TI2);                 \
          const float e = exp2f(lg2);                                         \
          const float pm = (rl == clab[ni]) ? lg2 : 0.f;                      \
          Srun[mi][r] += e; Prun[mi][r] += pm;                                \
          colE[ni] += e; colQ[ni] += pm;                                      \
        }                                                                     \
      }                                                                       \
    _Pragma("unroll")                                                         \
    for (int ni = 0; ni < 2; ni++) {                                          \
      float e = colE[ni], q = colQ[ni];                                       \
      e += __shfl_xor(e, 16, 64); e += __shfl_xor(e, 32, 64);                 \
      q += __shfl_xor(q, 16, 64); q += __shfl_xor(q, 32, 64);                 \
      if (quad == 0) {                                                        \
        atomicAdd(&colS[(c0) + ni * 16 + l15], e);                            \
        atomicAdd(&colP[(c0) + ni * 16 + l15], q * LN2F);                     \
      }                                                                       \
    }                                                                         \
  }

  // epilogue for the diagonal j-step: mask col==row, NO col-side
#define EPILOG_DIAG(c0)                                                       \
  {                                                                           \
    int clab[2];                                                              \
    clab[0] = glab[(c0) + l15];                                               \
    clab[1] = glab[(c0) + 16 + l15];                                          \
    _Pragma("unroll")                                                         \
    for (int mi = 0; mi < 2; mi++)                                            \
      _Pragma("unroll")                                                       \
      for (int r = 0; r < 4; r++) {                                           \
        const int row = r0 + mi * 16 + quad * 4 + r;                          \
        const int rl = rlab[mi][r];                                           \
        _Pragma("unroll")                                                     \
        for (int ni = 0; ni < 2; ni++) {                                      \
          const int col = (c0) + ni * 16 + l15;                               \
          const float lg2 = fmaf(acc[mi][ni][r], T1S2, -TI2);                 \
          const bool diag = (col == row);                                     \
          Srun[mi][r] += diag ? 0.f : exp2f(lg2);                             \
          Prun[mi][r] += (!diag && rl == clab[ni]) ? lg2 : 0.f;               \
        }                                                                     \
      }                                                                       \
  }

  if (ktiles == 4) {
    // A-fragments register-cached once for the whole strip
    i32x8 af[2][4];
    #pragma unroll
    for (int mi = 0; mi < 2; mi++)
      #pragma unroll
      for (int kt = 0; kt < 4; kt++)
        LOADF(af[mi][kt], (r0 >> 4) + mi, kt)

    for (int jb = a + s; jb < nstrips; jb += NS) {
      const int c0 = jb << 5;
      f32x4 acc[2][2];
      #pragma unroll
      for (int mi = 0; mi < 2; mi++)
        #pragma unroll
        for (int ni = 0; ni < 2; ni++) {
          f32x4 z = {0.f, 0.f, 0.f, 0.f};
          acc[mi][ni] = z;
        }
      // one load cluster per j-step, then one MFMA cluster
      i32x8 bv[2][4];
      #pragma unroll
      for (int ni = 0; ni < 2; ni++)
        #pragma unroll
        for (int kt = 0; kt < 4; kt++)
          LOADF(bv[ni][kt], (c0 >> 4) + ni, kt)
      #pragma unroll
      for (int kt = 0; kt < 4; kt++)
        #pragma unroll
        for (int mi = 0; mi < 2; mi++)
          #pragma unroll
          for (int ni = 0; ni < 2; ni++)
            acc[mi][ni] = __builtin_amdgcn_mfma_scale_f32_16x16x128_f8f6f4(
                af[mi][kt], bv[ni][kt], acc[mi][ni], 0, 0, 0, 127, 0, 127);
      if (jb == a) { EPILOG_DIAG(c0) } else { EPILOG_FAST(c0) }
    }
  } else {
    // generic fallback (D != 512): stream A and B per k-tile
    for (int jb = a + s; jb < nstrips; jb += NS) {
      const int c0 = jb << 5;
      f32x4 acc[2][2];
      #pragma unroll
      for (int mi = 0; mi < 2; mi++)
        #pragma unroll
        for (int ni = 0; ni < 2; ni++) {
          f32x4 z = {0.f, 0.f, 0.f, 0.f};
          acc[mi][ni] = z;
        }
      for (int kt = 0; kt < ktiles; kt++) {
        i32x8 a0, a1, b0, b1;
        LOADF(a0, (r0 >> 4) + 0, kt) LOADF(a1, (r0 >> 4) + 1, kt)
        LOADF(b0, (c0 >> 4) + 0, kt) LOADF(b1, (c0 >> 4) + 1, kt)
        acc[0][0] = __builtin_amdgcn_mfma_scale_f32_16x16x128_f8f6f4(
            a0, b0, acc[0][0], 0, 0, 0, 127, 0, 127);
        acc[0][1] = __builtin_amdgcn_mfma_scale_f32_16x16x128_f8f6f4(
            a0, b1, acc[0][1], 0, 0, 0, 127, 0, 127);
        acc[1][0] = __builtin_amdgcn_mfma_scale_f32_16x16x128_f8f6f4(
            a1, b0, acc[1][0], 0, 0, 0, 127, 0, 127);
        acc[1][1] = __builtin_amdgcn_mfma_scale_f32_16x16x128_f8f6f4(
            a1, b1, acc[1][1], 0, 0, 0, 127, 0, 127);
      }
      if (jb == a) { EPILOG_DIAG(c0) } else { EPILOG_FAST(c0) }
    }
  }
#undef LOADF
#undef EPILOG_FAST
#undef EPILOG_DIAG

  // one shuffle-reduce per strip; P scaled back to natural-log units
  #pragma unroll
  for (int mi = 0; mi < 2; mi++)
    #pragma unroll
    for (int r = 0; r < 4; r++) {
      float sv = Srun[mi][r], pv = Prun[mi][r];
      #pragma unroll
      for (int off = 1; off < 16; off <<= 1) {
        sv += __shfl_xor(sv, off, 64);
        pv += __shfl_xor(pv, off, 64);
      }
      if (l15 == 0) {
        const int row = r0 + mi * 16 + quad * 4 + r;
        partS[(size_t)row * NS + s] = sv;
        partP[(size_t)row * NS + s] = pv * LN2F;
      }
    }
}

// ---- per-row slice-sum (+ col-side) + histogram -> loss ----
__global__ __launch_bounds__(256) void reduce_loss_k(const float* __restrict__ partS,
                                                     const float* __restrict__ partP,
                                                     const float* __restrict__ colS,
                                                     const float* __restrict__ colP,
                                                     const int* __restrict__ glab,
                                                     const int* __restrict__ labels,
                                                     const int* __restrict__ kptr,
                                                     float* __restrict__ gacc,
                                                     int* __restrict__ dcnt,
                                                     float* __restrict__ out, int N) {
  const int tt = threadIdx.x;
  const int row = blockIdx.x * 256 + tt;
  const int k = *kptr;
  const int B = N / k;

  __shared__ int h[64];
  if (tt < 64) h[tt] = 0;
  __syncthreads();
  for (int g = tt; g < B; g += 256) {
    int lb = labels[(size_t)g * k];
    if (lb >= 0 && lb < 64) atomicAdd(&h[lb], 1);
  }
  __syncthreads();

  float l = 0.f, v = 0.f;
  if (row < N) {
    float S = colS[row], P = colP[row];
    #pragma unroll
    for (int s = 0; s < NS; s++) {
      S += partS[(size_t)row * NS + s];
      P += partP[(size_t)row * NS + s];
    }
    const int np = h[glab[row]] * k - 1;
    if (np > 0) {
      l = -(P - (float)np * logf(S + 1e-8f)) / (float)np;
      v = 1.f;
    }
  }
  #pragma unroll
  for (int off = 32; off; off >>= 1) {
    l += __shfl_xor(l, off, 64);
    v += __shfl_xor(v, off, 64);
  }
  __shared__ float sl4[4], sv4[4];
  if ((tt & 63) == 0) { sl4[tt >> 6] = l; sv4[tt >> 6] = v; }
  __syncthreads();
  if (tt == 0) {
    float L = 0.f, V = 0.f;
    #pragma unroll
    for (int i = 0; i < 4; i++) { L += sl4[i]; V += sv4[i]; }
    atomicAdd(&gacc[0], L);
    atomicAdd(&gacc[1], V);
    __threadfence();
    const int prev = atomicAdd(dcnt, 1);
    if (prev == (int)gridDim.x - 1) {
      const float Lf = atomicAdd(&gacc[0], 0.f);
      const float Vf = atomicAdd(&gacc[1], 0.f);
      out[0] = Lf / fmaxf(Vf, 1.f);
    }
  }
}

extern "C" void kernel_launch(void* const* d_in, const int* in_sizes, int n_in,
                              void* d_out, int out_size, void* d_ws, size_t ws_size,
                              hipStream_t stream) {
  const float* feat = (const float*)d_in[0];
  const int* labels = (const int*)d_in[1];
  const int* kptr   = (const int*)d_in[2];
  const int N = in_sizes[1];
  const int D = in_sizes[0] / N;  // 512

  char* ws = (char*)d_ws;
  uchar* fq = (uchar*)ws;
  size_t off = (size_t)N * D;  // fp8: 1 byte/elem
  float* partS = (float*)(ws + off); off += (size_t)N * NS * sizeof(float);
  float* partP = (float*)(ws + off); off += (size_t)N * NS * sizeof(float);
  float* colS  = (float*)(ws + off); off += (size_t)N * sizeof(float);
  float* colP  = (float*)(ws + off); off += (size_t)N * sizeof(float);
  int* glab    = (int*)(ws + off);   off += (size_t)N * sizeof(int);
  float* gacc  = (float*)(ws + off); off += 2 * sizeof(float);
  int* dcnt    = (int*)(ws + off);   off += sizeof(int);

  const int nstrips = N / 32;                  // 256
  const int ggrid = (nstrips / 2) * NS;        // 1024 blocks x 128 threads

  norm_k<<<(N + 3) / 4, 256, 0, stream>>>(feat, fq, labels, kptr, glab,
                                          colS, colP, gacc, dcnt, N, D);
  gemm_k<<<ggrid, 128, 0, stream>>>(fq, glab, partS, partP, colS, colP, N, D);
  reduce_loss_k<<<(N + 255) / 256, 256, 0, stream>>>(partS, partP, colS, colP,
                                                     glab, labels, kptr, gacc,
                                                     dcnt, (float*)d_out, N);
}